// Round 2
// baseline (303.665 us; speedup 1.0000x reference)
//
#include <hip/hip_runtime.h>
#include <math.h>

// Peak biquad (DF2T) over (16, 2, 1<<20) fp32.
//
// R3 post-mortem (99us, Occ 9.5%, VALUBusy 9.8%): double-buffered LDS
// (33KB) + 1024-block grid gave 1 wave/SIMD, and the compiler must
// conservatively drain vmcnt between global_load_lds and aliasing ds_reads
// -> zero overlap, full HBM latency exposed serially per tile, no second
// wave to hide it.
//
// R4: reg-staged prefetch (T14 issue-early / write-late). Next tile is
// loaded into 16 float4 VGPRs; the ds_write of those regs happens one full
// tile-compute later, so the load->use dependency is explicit through
// registers and the compiler emits exact COUNTED vmcnt waits (the 16
// y-stores issued in between keep the count >=16 -- never a drain to 0).
// Single 16KB LDS buffer + NT=4 -> 2048 blocks -> 8 blocks/CU = 2 waves
// per SIMD. XOR swizzle (kept from R3: conflicts 524288 -> 16384) applied
// identically on ds_write and ds_read. Lane63 -> lane0 __shfl carries exact
// filter state across tiles; only tile 0 needs a 64-sample global halo.
// One wave per block => no barriers; same-wave DS ops are in-order in HW.

constexpr int T_LEN   = 1 << 20;                 // samples per channel
constexpr int L_G     = 16;                      // granules (float4) per 64-sample chunk
constexpr int THREADS = 64;                      // one wave per block
constexpr int TILE_G  = THREADS * L_G;           // 1024 granules = 16 KiB
constexpr int NT      = 4;                       // tiles per block
constexpr int GRAN_PER_BLOCK  = NT * TILE_G;     // 4096
constexpr int GRAN_PER_CHAN   = T_LEN / 4;       // 262144
constexpr int BLOCKS_PER_CHAN = GRAN_PER_CHAN / GRAN_PER_BLOCK;  // 64

// Compiler fence + LDS drain at iteration boundary: stops any cross-
// iteration reordering of DS ops (store-phase reads vs next phase-W writes).
// Nearly free: store-phase ds_read data was already consumed by the stores.
#define LDSFENCE() asm volatile("s_waitcnt lgkmcnt(0)" ::: "memory")

__device__ __forceinline__ int swz(int row, int col) {
    // logical (row, col) -> LDS granule index (XOR swizzle inside each row);
    // uniform mod-8 bank-group distribution for every access phase.
    return (row << 4) | (col ^ (row & 15));
}

__global__ __launch_bounds__(THREADS, 2) void peak_kernel(
    const float4* __restrict__ x4,
    const float* __restrict__ p_freq_raw,
    const float* __restrict__ p_q_raw,
    const float* __restrict__ p_gain,
    float4* __restrict__ y4)
{
    __shared__ float4 buf[TILE_G];      // single x/y tile (swizzled), 16 KiB
    __shared__ float4 halo0[L_G];       // warm-up chunk for tile 0, thread 0

    const int t = threadIdx.x;
    const size_t tb0 = (size_t)blockIdx.x * GRAN_PER_BLOCK;
    const bool chan_start = (blockIdx.x % BLOCKS_PER_CHAN) == 0;

    // ---- coefficients (cheap scalar math; overlaps with loads) ----
    float fraw = p_freq_raw[0];
    float qraw = p_q_raw[0];
    float gdb  = p_gain[0];

    float sfreq = 1.0f / (1.0f + __expf(-fraw));
    float freq  = sfreq * (17500.0f - 33.0f) + 33.0f;
    float sq    = 1.0f / (1.0f + __expf(-qraw));
    float Q     = sq * (20.0f - 0.2f) + 0.2f;

    float w0    = 6.283185307179586f * freq / 44100.0f;
    float A     = expf(gdb * 0.05756462732485114f);   // 10^(g/40)
    float sw    = sinf(w0);
    float cw    = cosf(w0);
    float alpha = sw / (2.0f * Q);

    float inv_a0 = 1.0f / (1.0f + alpha / A);
    float b0  = (1.0f + alpha * A) * inv_a0;
    float b1  = (-2.0f * cw) * inv_a0;
    float b2  = (1.0f - alpha * A) * inv_a0;
    float na1 = -b1;
    float na2 = -((1.0f - alpha / A) * inv_a0);

    // ---- prologue: halo first (oldest vmem op -> counted wait), then the
    //      tile-0 prefetch batch into registers ----
    float4 h0 = make_float4(0.f, 0.f, 0.f, 0.f);
    if (t < L_G && !chan_start) h0 = x4[tb0 - L_G + t];

    float4 P[L_G];                       // prefetch bank: 64 VGPRs
#pragma unroll
    for (int i = 0; i < L_G; ++i) P[i] = x4[tb0 + ((i << 6) | t)];

    if (t < L_G) halo0[t] = h0;          // waits vmcnt(16): P stays in flight

    float s1 = 0.f, s2 = 0.f;            // running DF2T state

#pragma unroll 1
    for (int k = 0; k < NT; ++k) {
        const size_t gb = tb0 + (size_t)k * TILE_G;

        LDSFENCE();

        // ---- Phase W: prefetched regs -> LDS (swizzled). Compiler inserts
        //      counted vmcnt here for the P loads (stores issued after them
        //      keep the floor at vmcnt(16) in steady state). ----
#pragma unroll
        for (int i = 0; i < L_G; ++i) {
            const int p = (i << 6) | t;           // linear granule index
            buf[swz(p >> 4, p & 15)] = P[i];
        }

        // ---- issue next tile's loads immediately (P regs now free);
        //      they stay in flight across warm-up + main + store ----
        if (k + 1 < NT) {
#pragma unroll
            for (int i = 0; i < L_G; ++i)
                P[i] = x4[gb + TILE_G + ((i << 6) | t)];
        }

        // exact state carry: lane 63's end state -> lane 0 of next tile
        const float cs1 = __shfl(s1, 63);
        const float cs2 = __shfl(s2, 63);

        // ---- warm-up (64 samples, discard outputs) ----
        // t>0: previous chunk = row t-1; t==0,k==0: halo0; t==0,k>0: dummy
        // row 0 (result replaced by carried state).
        const float4* wbase;
        int wmask;
        if (t == 0) { wbase = (k == 0) ? &halo0[0] : &buf[0]; wmask = 0; }
        else        { wbase = &buf[(t - 1) << 4]; wmask = (t - 1) & 15; }

        float a1s = 0.f, a2s = 0.f;
#pragma unroll
        for (int j = 0; j < L_G; ++j) {
            float4 xv = wbase[j ^ wmask];
#pragma unroll
            for (int q = 0; q < 4; ++q) {
                float xt = (&xv.x)[q];
                float yv = fmaf(b0, xt, a1s);
                a1s = fmaf(b1, xt, a2s);
                a1s = fmaf(na1, yv, a1s);
                a2s = xt * b2;
                a2s = fmaf(na2, yv, a2s);
            }
        }
        {
            const bool carry = (t == 0) && (k > 0);
            s1 = carry ? cs1 : a1s;
            s2 = carry ? cs2 : a2s;
        }

        // ---- main pass: own chunk (row t), overwrite x with y in place.
        //      Cross-lane RAW/WAR through LDS is safe: same wave, in-order
        //      DS pipe, program order read-before-write. ----
        {
            float4* mbase = &buf[t << 4];
            const int mmask = t & 15;
#pragma unroll
            for (int j = 0; j < L_G; ++j) {
                float4 xv = mbase[j ^ mmask];
                float4 ov;
#pragma unroll
                for (int q = 0; q < 4; ++q) {
                    float xt = (&xv.x)[q];
                    float yv = fmaf(b0, xt, s1);
                    s1 = fmaf(b1, xt, s2);
                    s1 = fmaf(na1, yv, s1);
                    s2 = xt * b2;
                    s2 = fmaf(na2, yv, s2);
                    (&ov.x)[q] = yv;
                }
                mbase[j ^ mmask] = ov;
            }
        }

        // ---- store phase: coalesced LDS -> global (exactly 16 store ops:
        //      these pad the vmcnt count so the next phase-W wait never
        //      drains the in-flight prefetch) ----
#pragma unroll
        for (int i = 0; i < L_G; ++i) {
            const int p = (i << 6) | t;
            y4[gb + p] = buf[swz(p >> 4, p & 15)];
        }
    }
}

extern "C" void kernel_launch(void* const* d_in, const int* in_sizes, int n_in,
                              void* d_out, int out_size, void* d_ws, size_t ws_size,
                              hipStream_t stream)
{
    const float4* x4 = (const float4*)d_in[0];
    const float*  fr = (const float*)d_in[1];
    const float*  qr = (const float*)d_in[2];
    const float*  gn = (const float*)d_in[3];
    float4*       y4 = (float4*)d_out;

    int n_channels = in_sizes[0] / T_LEN;                 // 32
    int n_blocks   = n_channels * BLOCKS_PER_CHAN;        // 2048

    hipLaunchKernelGGL(peak_kernel, dim3(n_blocks), dim3(THREADS), 0, stream,
                       x4, fr, qr, gn, y4);
}

// Round 3
// 246.068 us; speedup vs baseline: 1.2341x; 1.2341x over previous
//
#include <hip/hip_runtime.h>
#include <math.h>

// Peak biquad (DF2T) over (16, 2, 1<<20) fp32.
//
// R4 post-mortem (143us): WRITE_SIZE doubled (+134MB) + FETCH +66MB with
// VGPR_Count=72 -> the float4 P[16] prefetch bank SPILLED to scratch
// (global->reg->scratch->reg->LDS, +200MB traffic, load->use serialized).
// The schedule itself was right (occupancy doubled to 19.7% as predicted).
//
// R5: same schedule, prefetch bank as 16 NAMED float4 registers (no array
// aggregate, no conditional definition -> nothing for the spill heuristic
// to target). Prefetch is unconditional with a clamped base (last iter
// harmlessly re-loads the current tile) so every iteration has identical
// vmcnt arithmetic: 16 loads issued right after the LDS-write phase frees
// the bank, 16 y-stores pad the queue, next iteration's consumption waits
// on a COUNTED vmcnt(16) -- never a drain to 0. Single 16KB LDS buffer,
// 2048 blocks -> 8 blocks/CU = 2 waves/SIMD; intra-wave prefetch hides HBM
// latency under ~1us of dependent FMA chain; second wave covers residue.
// XOR swizzle on both LDS sides (conflict-free b128 phases). Lane63->lane0
// __shfl carries exact state; only tile 0 warms up from a global halo.

constexpr int T_LEN   = 1 << 20;                 // samples per channel
constexpr int L_G     = 16;                      // granules (float4) per 64-sample chunk
constexpr int THREADS = 64;                      // one wave per block
constexpr int TILE_G  = THREADS * L_G;           // 1024 granules = 16 KiB
constexpr int NT      = 4;                       // tiles per block
constexpr int GRAN_PER_BLOCK  = NT * TILE_G;     // 4096
constexpr int GRAN_PER_CHAN   = T_LEN / 4;       // 262144
constexpr int BLOCKS_PER_CHAN = GRAN_PER_CHAN / GRAN_PER_BLOCK;  // 64

// Compiler fence + LDS drain at iteration boundary (WAR: store-phase reads
// vs phase-W writes). Same-wave DS is in-order in HW; this stops compiler
// reordering. Cheap: the drained ds_reads were already consumed.
#define LDSFENCE() asm volatile("s_waitcnt lgkmcnt(0)" ::: "memory")

__device__ __forceinline__ int swz(int row, int col) {
    // logical (row, col) -> LDS granule index (XOR swizzle inside each row)
    return (row << 4) | (col ^ (row & 15));
}

// prefetch-bank ops, all indices compile-time constant
#define PL(i, Pr, gb_) Pr = x4[(gb_) + (((i) << 6) | t)]
#define PW(i, Pr) do {                                   \
        const int p_ = ((i) << 6) | t;                   \
        buf[swz(p_ >> 4, p_ & 15)] = (Pr);               \
    } while (0)

#define PL_ALL(gb_)                                                   \
    PL(0,P0,gb_);  PL(1,P1,gb_);  PL(2,P2,gb_);  PL(3,P3,gb_);        \
    PL(4,P4,gb_);  PL(5,P5,gb_);  PL(6,P6,gb_);  PL(7,P7,gb_);        \
    PL(8,P8,gb_);  PL(9,P9,gb_);  PL(10,P10,gb_); PL(11,P11,gb_);     \
    PL(12,P12,gb_); PL(13,P13,gb_); PL(14,P14,gb_); PL(15,P15,gb_)

#define PW_ALL()                                         \
    PW(0,P0);  PW(1,P1);  PW(2,P2);  PW(3,P3);           \
    PW(4,P4);  PW(5,P5);  PW(6,P6);  PW(7,P7);           \
    PW(8,P8);  PW(9,P9);  PW(10,P10); PW(11,P11);        \
    PW(12,P12); PW(13,P13); PW(14,P14); PW(15,P15)

__global__ __launch_bounds__(THREADS, 2) void peak_kernel(
    const float4* __restrict__ x4,
    const float* __restrict__ p_freq_raw,
    const float* __restrict__ p_q_raw,
    const float* __restrict__ p_gain,
    float4* __restrict__ y4)
{
    __shared__ float4 buf[TILE_G];      // single x/y tile (swizzled), 16 KiB
    __shared__ float4 halo0[L_G];       // warm-up chunk for tile 0, thread 0

    const int t = threadIdx.x;
    const size_t tb0 = (size_t)blockIdx.x * GRAN_PER_BLOCK;
    const bool chan_start = (blockIdx.x % BLOCKS_PER_CHAN) == 0;

    // ---- coefficients (cheap scalar math; overlaps with loads) ----
    float fraw = p_freq_raw[0];
    float qraw = p_q_raw[0];
    float gdb  = p_gain[0];

    float sfreq = 1.0f / (1.0f + __expf(-fraw));
    float freq  = sfreq * (17500.0f - 33.0f) + 33.0f;
    float sq    = 1.0f / (1.0f + __expf(-qraw));
    float Q     = sq * (20.0f - 0.2f) + 0.2f;

    float w0    = 6.283185307179586f * freq / 44100.0f;
    float A     = expf(gdb * 0.05756462732485114f);   // 10^(g/40)
    float sw    = sinf(w0);
    float cw    = cosf(w0);
    float alpha = sw / (2.0f * Q);

    float inv_a0 = 1.0f / (1.0f + alpha / A);
    float b0  = (1.0f + alpha * A) * inv_a0;
    float b1  = (-2.0f * cw) * inv_a0;
    float b2  = (1.0f - alpha * A) * inv_a0;
    float na1 = -b1;
    float na2 = -((1.0f - alpha / A) * inv_a0);

    // ---- prologue: halo first (oldest vmem op), then tile-0 prefetch ----
    float4 h0 = make_float4(0.f, 0.f, 0.f, 0.f);
    if (t < L_G && !chan_start) h0 = x4[tb0 - L_G + t];

    float4 P0,P1,P2,P3,P4,P5,P6,P7,P8,P9,P10,P11,P12,P13,P14,P15;
    PL_ALL(tb0);

    if (t < L_G) halo0[t] = h0;   // counted wait for h0 only; P stays in flight

    float s1 = 0.f, s2 = 0.f;     // running DF2T state

#pragma unroll 1
    for (int k = 0; k < NT; ++k) {
        const size_t gb = tb0 + (size_t)k * TILE_G;

        LDSFENCE();

        // ---- Phase W: prefetch regs -> LDS (swizzled); compiler emits a
        //      counted vmcnt wait for the bank here ----
        PW_ALL();

        // ---- re-issue the bank for the next tile immediately (clamped on
        //      the last iteration -> identical wait arithmetic every iter;
        //      loads stay in flight across warm-up + main + store) ----
        {
            const size_t nb = (k + 1 < NT) ? gb + TILE_G : gb;
            PL_ALL(nb);
        }

        // exact state carry: lane 63's end state -> lane 0 of next tile
        const float cs1 = __shfl(s1, 63);
        const float cs2 = __shfl(s2, 63);

        // ---- warm-up (64 samples, discard outputs) ----
        // t>0: previous chunk = row t-1; t==0,k==0: halo0; t==0,k>0: dummy
        // row 0 (result replaced by carried state).
        const float4* wbase;
        int wmask;
        if (t == 0) { wbase = (k == 0) ? &halo0[0] : &buf[0]; wmask = 0; }
        else        { wbase = &buf[(t - 1) << 4]; wmask = (t - 1) & 15; }

        float a1s = 0.f, a2s = 0.f;
#pragma unroll
        for (int j = 0; j < L_G; ++j) {
            float4 xv = wbase[j ^ wmask];
#pragma unroll
            for (int q = 0; q < 4; ++q) {
                float xt = (&xv.x)[q];
                float yv = fmaf(b0, xt, a1s);
                a1s = fmaf(b1, xt, a2s);
                a1s = fmaf(na1, yv, a1s);
                a2s = xt * b2;
                a2s = fmaf(na2, yv, a2s);
            }
        }
        {
            const bool carry = (t == 0) && (k > 0);
            s1 = carry ? cs1 : a1s;
            s2 = carry ? cs2 : a2s;
        }

        // ---- main pass: own chunk (row t), overwrite x with y in place.
        //      Same-wave in-order DS pipe makes the cross-lane WAR safe. ----
        {
            float4* mbase = &buf[t << 4];
            const int mmask = t & 15;
#pragma unroll
            for (int j = 0; j < L_G; ++j) {
                float4 xv = mbase[j ^ mmask];
                float4 ov;
#pragma unroll
                for (int q = 0; q < 4; ++q) {
                    float xt = (&xv.x)[q];
                    float yv = fmaf(b0, xt, s1);
                    s1 = fmaf(b1, xt, s2);
                    s1 = fmaf(na1, yv, s1);
                    s2 = xt * b2;
                    s2 = fmaf(na2, yv, s2);
                    (&ov.x)[q] = yv;
                }
                mbase[j ^ mmask] = ov;
            }
        }

        // ---- store phase: coalesced LDS -> global (exactly 16 store ops:
        //      they pad vmcnt so the next phase-W wait never drains the
        //      in-flight prefetch) ----
#pragma unroll
        for (int i = 0; i < L_G; ++i) {
            const int p = (i << 6) | t;
            y4[gb + p] = buf[swz(p >> 4, p & 15)];
        }
    }
}

extern "C" void kernel_launch(void* const* d_in, const int* in_sizes, int n_in,
                              void* d_out, int out_size, void* d_ws, size_t ws_size,
                              hipStream_t stream)
{
    const float4* x4 = (const float4*)d_in[0];
    const float*  fr = (const float*)d_in[1];
    const float*  qr = (const float*)d_in[2];
    const float*  gn = (const float*)d_in[3];
    float4*       y4 = (float4*)d_out;

    int n_channels = in_sizes[0] / T_LEN;                 // 32
    int n_blocks   = n_channels * BLOCKS_PER_CHAN;        // 2048

    hipLaunchKernelGGL(peak_kernel, dim3(n_blocks), dim3(THREADS), 0, stream,
                       x4, fr, qr, gn, y4);
}

// Round 4
// 236.104 us; speedup vs baseline: 1.2862x; 1.0422x over previous
//
#include <hip/hip_runtime.h>
#include <math.h>

// Peak biquad (DF2T) over (16, 2, 1<<20) fp32.
//
// R5 post-mortem (87us, 2.4 TB/s): spill fixed (VGPR 128, traffic normal)
// but STILL ~3 TB/s delivered vs 6.3 TB/s copy ubench. Equilibrium math:
// per-wave tile period settled at 21.8us while the wave's serial critical
// path is ~1us -- the wave sleeps with ZERO loads outstanding most of the
// period. A single wave can only keep one 16KB prefetch batch in flight;
// latency hiding must come from MORE WAVES. Occupancy has been LDS-bound
// at ~8 waves/CU (16-17KB per 1-wave block) in every variant so far.
//
// R6: shrink the granule, multiply the waves. 32-sample chunks (8 granules)
// -> 8.4KB LDS per 1-wave block -> ~16+ blocks/CU resident; 16384 one-shot
// blocks, lifetime ~1us each, so every CU always has several blocks in
// their staging phase with 9KB batches in flight (classic high-occupancy
// streaming, like the copy ubench). Warm-up stays 64 samples (rows t,t+1
// of the halo-extended tile) -> accuracy unchanged; compute redundancy 3x
// (still only ~15-20% VALU). XOR swizzle kept (conflicts were negligible).
// No prefetch bank -> ~64 VGPR, no spill surface.

constexpr int T_LEN   = 1 << 20;                 // samples per channel
constexpr int CH_G    = 8;                       // granules (float4) per 32-sample chunk
constexpr int THREADS = 64;                      // one wave per block
constexpr int HALO_R  = 2;                       // 2 chunk-rows = 64 warm-up samples
constexpr int ROWS    = THREADS + HALO_R;        // 66 LDS rows
constexpr int GRAN_PER_BLOCK  = THREADS * CH_G;  // 512 granules = 8 KiB
constexpr int GRAN_PER_CHAN   = T_LEN / 4;       // 262144
constexpr int BLOCKS_PER_CHAN = GRAN_PER_CHAN / GRAN_PER_BLOCK;  // 512

__device__ __forceinline__ int swz(int row, int col) {
    // logical (row, col<8) -> LDS granule index; XOR spreads the 64 lanes'
    // same-column accesses across all 8 bank-groups (proven in R5: conflict
    // counter collapsed to noise).
    return (row << 3) | (col ^ (row & 7));
}

__global__ __launch_bounds__(THREADS, 4) void peak_kernel(
    const float4* __restrict__ x4,
    const float* __restrict__ p_freq_raw,
    const float* __restrict__ p_q_raw,
    const float* __restrict__ p_gain,
    float4* __restrict__ y4)
{
    __shared__ float4 buf[ROWS * CH_G];          // 528 granules = 8448 B

    const int t = threadIdx.x;
    const size_t base = (size_t)blockIdx.x * GRAN_PER_BLOCK;
    const bool chan_start = (blockIdx.x % BLOCKS_PER_CHAN) == 0;

    // ---- coefficients (scalar math; overlaps with staging loads) ----
    float fraw = p_freq_raw[0];
    float qraw = p_q_raw[0];
    float gdb  = p_gain[0];

    float sfreq = 1.0f / (1.0f + __expf(-fraw));
    float freq  = sfreq * (17500.0f - 33.0f) + 33.0f;
    float sq    = 1.0f / (1.0f + __expf(-qraw));
    float Q     = sq * (20.0f - 0.2f) + 0.2f;

    float w0    = 6.283185307179586f * freq / 44100.0f;
    float A     = expf(gdb * 0.05756462732485114f);   // 10^(g/40)
    float sw    = sinf(w0);
    float cw    = cosf(w0);
    float alpha = sw / (2.0f * Q);

    float inv_a0 = 1.0f / (1.0f + alpha / A);
    float b0  = (1.0f + alpha * A) * inv_a0;
    float b1  = (-2.0f * cw) * inv_a0;
    float b2  = (1.0f - alpha * A) * inv_a0;
    float na1 = -b1;
    float na2 = -((1.0f - alpha / A) * inv_a0);

    // ---- stage: global -> LDS, all loads issued back-to-back ----
    // halo rows 0..1 = the 64 samples preceding this block's region
    if (t < HALO_R * CH_G) {                     // lanes 0..15
        float4 h = make_float4(0.f, 0.f, 0.f, 0.f);
        if (!chan_start) h = x4[base - HALO_R * CH_G + t];
        buf[swz(t >> 3, t & 7)] = h;
    }
    // tile rows 2..65 (8 coalesced 1KB wave-loads)
#pragma unroll
    for (int i = 0; i < CH_G; ++i) {
        const int g = (i << 6) | t;              // 0..511, lane-contiguous
        buf[swz(HALO_R + (g >> 3), g & 7)] = x4[base + g];
    }
    __syncthreads();

    // ---- warm-up: 64 samples = extended rows t, t+1 (discard outputs) ----
    float s1 = 0.f, s2 = 0.f;
#pragma unroll
    for (int r = 0; r < HALO_R; ++r) {
        const int row = t + r;
#pragma unroll
        for (int j = 0; j < CH_G; ++j) {
            float4 xv = buf[swz(row, j)];
#pragma unroll
            for (int q = 0; q < 4; ++q) {
                float xt = (&xv.x)[q];
                float yv = fmaf(b0, xt, s1);
                s1 = fmaf(b1, xt, s2);
                s1 = fmaf(na1, yv, s1);
                s2 = xt * b2;
                s2 = fmaf(na2, yv, s2);
            }
        }
    }
    __syncthreads();   // all warm-up reads done before rows are overwritten

    // ---- main: own chunk = extended row t+2, overwrite x with y ----
    {
        const int mrow = t + HALO_R;
#pragma unroll
        for (int j = 0; j < CH_G; ++j) {
            float4 xv = buf[swz(mrow, j)];
            float4 ov;
#pragma unroll
            for (int q = 0; q < 4; ++q) {
                float xt = (&xv.x)[q];
                float yv = fmaf(b0, xt, s1);
                s1 = fmaf(b1, xt, s2);
                s1 = fmaf(na1, yv, s1);
                s2 = xt * b2;
                s2 = fmaf(na2, yv, s2);
                (&ov.x)[q] = yv;
            }
            buf[swz(mrow, j)] = ov;
        }
    }
    __syncthreads();

    // ---- store: LDS -> global (8 coalesced 1KB wave-stores) ----
#pragma unroll
    for (int i = 0; i < CH_G; ++i) {
        const int g = (i << 6) | t;
        y4[base + g] = buf[swz(HALO_R + (g >> 3), g & 7)];
    }
}

extern "C" void kernel_launch(void* const* d_in, const int* in_sizes, int n_in,
                              void* d_out, int out_size, void* d_ws, size_t ws_size,
                              hipStream_t stream)
{
    const float4* x4 = (const float4*)d_in[0];
    const float*  fr = (const float*)d_in[1];
    const float*  qr = (const float*)d_in[2];
    const float*  gn = (const float*)d_in[3];
    float4*       y4 = (float4*)d_out;

    int n_channels = in_sizes[0] / T_LEN;                 // 32
    int n_blocks   = n_channels * BLOCKS_PER_CHAN;        // 16384

    hipLaunchKernelGGL(peak_kernel, dim3(n_blocks), dim3(THREADS), 0, stream,
                       x4, fr, qr, gn, y4);
}